// Round 4
// baseline (39.011 us; speedup 1.0000x reference)
//
#include <hip/hip_runtime.h>
#include <math.h>

#define NLAB 2000
#define BATCH 1024
#define LAMBDA_SMOOTH 0.1f

#define RPG 8            // batch rows per group
#define NRG 128          // row groups (1024/8)
#define K1_SL 8          // label slices per row group in K1
#define K1_LPS 250       // labels per slice
#define ES 8             // edge slices in K2
#define NB2 1024         // K2 grid = 128 rg x 8 es
#define IMG_U16 18000    // padded image: (2000 + 2000/8)*8 u16 = 36000 B
#define IMG_V4  2250     // same in uint4

// u16 slot of (label l, row 0): 8 u16 per label + one 16B pad granule per 8 labels.
// slotOf(l) is always a multiple of 8 u16 = 16 B -> any label-range split is 16B-aligned.
__device__ __forceinline__ int slotOf(int l) { return (l + (l >> 3)) << 3; }

__device__ __forceinline__ ushort f2bf(float f) {   // round-to-nearest-even bf16
    unsigned u = __float_as_uint(f);
    return (ushort)((u + 0x7fffu + ((u >> 16) & 1u)) >> 16);
}
__device__ __forceinline__ float bf_lo(unsigned u) { return __uint_as_float(u << 16); }
__device__ __forceinline__ float bf_hi(unsigned u) { return __uint_as_float(u & 0xffff0000u); }

// ---------------------------------------------------------------------------
// K1: convert + pack-transpose. grid 1024: rg = bid>>3, slice = bid&7.
// Each block: 8 batch rows x 250 labels -> slice of the rg image, staged in
// LDS, streamed out linearly (16B-aligned since slotOf(l0) % 8 == 0).
// 4 blocks/CU, 16 waves/CU -> HBM latency hidden. Also resets K2's counter.
// ---------------------------------------------------------------------------
__global__ __launch_bounds__(256) void convert_pack_kernel(
        const float* __restrict__ logits, const float* __restrict__ labels,
        uint4* __restrict__ yPack, unsigned* __restrict__ cnt) {
    __shared__ ushort sh[2304];                 // max slice span = 2256 u16
    const int rg  = blockIdx.x >> 3;
    const int s   = blockIdx.x & 7;
    const int tid = threadIdx.x;
    if (blockIdx.x == 0 && tid == 0) *cnt = 0;  // reset completion counter for K2

    const int l0 = s * K1_LPS;
    const int u0 = slotOf(l0);                  // 16B-aligned u16 start
    const int u1 = slotOf(l0 + K1_LPS);         // end
    if (tid < K1_LPS) {
        const int l  = l0 + tid;
        const int us = slotOf(l) - u0;
#pragma unroll
        for (int r = 0; r < RPG; ++r) {
            const int idx = (rg * RPG + r) * NLAB + l;   // coalesced in tid
            const float lg  = logits[idx];
            const float lab = labels[idx];
            const float sg  = 1.0f / (1.0f + __expf(-lg));
            const bool ann  = (lab == 0.0f) || (lab == 1.0f);
            const float y   = ann ? (2.0f * lab - 1.0f) : (2.0f * sg - 1.0f);
            sh[us + r] = f2bf(y);
        }
    }
    __syncthreads();
    const int nV4 = (u1 - u0) >> 3;
    const uint4* shv = (const uint4*)sh;
    uint4* dst = yPack + (size_t)rg * IMG_V4 + (u0 >> 3);
    for (int i = tid; i < nV4; i += 256) dst[i] = shv[i];
}

// ---------------------------------------------------------------------------
// K2: edge reduction + fused final reduce.
// Block map keeps all 8 es-blocks of one rg on the SAME XCD (bid&7 ~ XCD):
//   x = bid&7, j = bid>>3, rg = x*16 + (j&15), es = j>>4
// -> each image is pulled from L3 once per XCD, then 7x L2 hits.
// Each lane owns an edge: coalesced index loads + two ds_read_b128 gathers
// (left column ~broadcast since left_idx is sorted; right column random).
// Last block (fence + atomic counter) sums the 1024 partials in fixed order.
// ---------------------------------------------------------------------------
__global__ __launch_bounds__(256) void edge_reduce_kernel(
        const uint4* __restrict__ yPack, const float* __restrict__ ew,
        const int* __restrict__ li, const int* __restrict__ ri,
        int nEdges, float* __restrict__ partials, unsigned* __restrict__ cnt,
        float scale, float* __restrict__ out) {
    __shared__ uint4 shv[IMG_V4];               // 36000 B
    __shared__ float red[4];
    __shared__ int lastFlag;
    const int x   = blockIdx.x & 7;             // XCD slot
    const int j   = blockIdx.x >> 3;
    const int rg  = x * 16 + (j & 15);
    const int es  = j >> 4;
    const int tid = threadIdx.x;

    const uint4* src = yPack + (size_t)rg * IMG_V4;
    for (int i = tid; i < IMG_V4; i += 256) shv[i] = src[i];
    __syncthreads();
    const ushort* sh = (const ushort*)shv;

    const int per = (nEdges + ES - 1) / ES;
    const int e0  = es * per;
    int e1 = e0 + per; if (e1 > nEdges) e1 = nEdges;

    float acc = 0.0f;
#pragma unroll 2
    for (int e = e0 + tid; e < e1; e += 256) {
        const int   l = li[e];
        const int   r = ri[e];
        const float w = ew[e];
        const uint4 A = *(const uint4*)(sh + slotOf(l));   // 8 rows, left col
        const uint4 B = *(const uint4*)(sh + slotOf(r));   // 8 rows, right col
        float s = 0.0f;
        float d;
        d = bf_lo(A.x) - bf_lo(B.x); s = fmaf(d, d, s);
        d = bf_hi(A.x) - bf_hi(B.x); s = fmaf(d, d, s);
        d = bf_lo(A.y) - bf_lo(B.y); s = fmaf(d, d, s);
        d = bf_hi(A.y) - bf_hi(B.y); s = fmaf(d, d, s);
        d = bf_lo(A.z) - bf_lo(B.z); s = fmaf(d, d, s);
        d = bf_hi(A.z) - bf_hi(B.z); s = fmaf(d, d, s);
        d = bf_lo(A.w) - bf_lo(B.w); s = fmaf(d, d, s);
        d = bf_hi(A.w) - bf_hi(B.w); s = fmaf(d, d, s);
        acc = fmaf(w, s, acc);
    }

#pragma unroll
    for (int off = 32; off > 0; off >>= 1)
        acc += __shfl_down(acc, off, 64);
    if ((tid & 63) == 0) red[tid >> 6] = acc;
    __syncthreads();
    if (tid == 0) {
        partials[blockIdx.x] = red[0] + red[1] + red[2] + red[3];
        __threadfence();                         // release partials (device scope)
        const unsigned old = atomicAdd(cnt, 1u);
        lastFlag = (old == (unsigned)(NB2 - 1));
    }
    __syncthreads();
    if (lastFlag) {                              // exactly one block; fixed sum order
        __threadfence();                         // acquire all partials
        float s = 0.0f;
        for (int i = tid; i < NB2; i += 256) s += partials[i];
#pragma unroll
        for (int off = 32; off > 0; off >>= 1)
            s += __shfl_down(s, off, 64);
        if ((tid & 63) == 0) red[tid >> 6] = s;
        __syncthreads();
        if (tid == 0) out[0] = scale * (red[0] + red[1] + red[2] + red[3]);
    }
}

// ---------------------------------------------------------------------------
extern "C" void kernel_launch(void* const* d_in, const int* in_sizes, int n_in,
                              void* d_out, int out_size, void* d_ws, size_t ws_size,
                              hipStream_t stream) {
    const float* logits = (const float*)d_in[0];
    const float* labels = (const float*)d_in[1];
    const float* ew     = (const float*)d_in[2];
    const int*   li     = (const int*)d_in[3];
    const int*   ri     = (const int*)d_in[4];
    float* out          = (float*)d_out;

    const int nEdges = in_sizes[2];

    // workspace: yPack images (128 * 36000 B), partials (4 KB), counter
    uint4*    yPack    = (uint4*)d_ws;
    float*    partials = (float*)((char*)d_ws + (size_t)NRG * IMG_U16 * sizeof(ushort));
    unsigned* cnt      = (unsigned*)(partials + NB2);

    convert_pack_kernel<<<NRG * K1_SL, 256, 0, stream>>>(logits, labels, yPack, cnt);

    const float scale = LAMBDA_SMOOTH / ((float)BATCH * (float)nEdges);
    edge_reduce_kernel<<<NB2, 256, 0, stream>>>(yPack, ew, li, ri, nEdges,
                                                partials, cnt, scale, out);
}

// Round 5
// 21.585 us; speedup vs baseline: 1.8074x; 1.8074x over previous
//
#include <hip/hip_runtime.h>
#include <math.h>

#define NLAB 2000
#define BATCH 1024
#define LAMBDA_SMOOTH 0.1f

#define RPG 8            // batch rows per group
#define NRG 128          // row groups (1024/8)
#define K1_SL 8          // label slices per row group in K1
#define K1_LPS 250       // labels per slice
#define ES 8             // edge slices in K2
#define NB2 1024         // K2 grid = 128 rg x 8 es
#define IMG_U16 18000    // padded image: (2000 + 2000/8)*8 u16 = 36000 B
#define IMG_V4  2250     // same in uint4

// u16 slot of (label l, row 0): 8 u16 per label + one 16B pad granule per 8 labels.
__device__ __forceinline__ int slotOf(int l) { return (l + (l >> 3)) << 3; }

__device__ __forceinline__ ushort f2bf(float f) {   // round-to-nearest-even bf16
    unsigned u = __float_as_uint(f);
    return (ushort)((u + 0x7fffu + ((u >> 16) & 1u)) >> 16);
}
__device__ __forceinline__ float bf_lo(unsigned u) { return __uint_as_float(u << 16); }
__device__ __forceinline__ float bf_hi(unsigned u) { return __uint_as_float(u & 0xffff0000u); }

// ---------------------------------------------------------------------------
// K1: convert + pack-transpose. grid 1024: rg = bid>>3, slice = bid&7.
// Each block: 8 batch rows x 250 labels -> slice of the rg image, staged in
// LDS, streamed out linearly (16B-aligned since slotOf(l0) % 8 == 0).
// 4 blocks/CU, 16 waves/CU.
// ---------------------------------------------------------------------------
__global__ __launch_bounds__(256) void convert_pack_kernel(
        const float* __restrict__ logits, const float* __restrict__ labels,
        uint4* __restrict__ yPack) {
    __shared__ ushort sh[2304];                 // max slice span = 2256 u16
    const int rg  = blockIdx.x >> 3;
    const int s   = blockIdx.x & 7;
    const int tid = threadIdx.x;

    const int l0 = s * K1_LPS;
    const int u0 = slotOf(l0);                  // 16B-aligned u16 start
    const int u1 = slotOf(l0 + K1_LPS);         // end
    if (tid < K1_LPS) {
        const int l  = l0 + tid;
        const int us = slotOf(l) - u0;
#pragma unroll
        for (int r = 0; r < RPG; ++r) {
            const int idx = (rg * RPG + r) * NLAB + l;   // coalesced in tid
            const float lg  = logits[idx];
            const float lab = labels[idx];
            const float sg  = 1.0f / (1.0f + __expf(-lg));
            const bool ann  = (lab == 0.0f) || (lab == 1.0f);
            const float y   = ann ? (2.0f * lab - 1.0f) : (2.0f * sg - 1.0f);
            sh[us + r] = f2bf(y);
        }
    }
    __syncthreads();
    const int nV4 = (u1 - u0) >> 3;
    const uint4* shv = (const uint4*)sh;
    uint4* dst = yPack + (size_t)rg * IMG_V4 + (u0 >> 3);
    for (int i = tid; i < nV4; i += 256) dst[i] = shv[i];
}

// ---------------------------------------------------------------------------
// K2: edge reduction. Block map keeps all 8 es-blocks of one rg on the
// SAME XCD (bid&7 ~ XCD):  x = bid&7, j = bid>>3, rg = x*16 + (j&15), es = j>>4
// -> each image pulled from L3 once per XCD, then served from L2.
// Each lane owns an edge: coalesced index loads + two ds_read_b128 gathers.
// One partial per block; NO cross-block atomics (that cost ~10 us in R4).
// ---------------------------------------------------------------------------
__global__ __launch_bounds__(256) void edge_reduce_kernel(
        const uint4* __restrict__ yPack, const float* __restrict__ ew,
        const int* __restrict__ li, const int* __restrict__ ri,
        int nEdges, float* __restrict__ partials) {
    __shared__ uint4 shv[IMG_V4];               // 36000 B
    __shared__ float red[4];
    const int x   = blockIdx.x & 7;             // XCD slot
    const int j   = blockIdx.x >> 3;
    const int rg  = x * 16 + (j & 15);
    const int es  = j >> 4;
    const int tid = threadIdx.x;

    const uint4* src = yPack + (size_t)rg * IMG_V4;
    for (int i = tid; i < IMG_V4; i += 256) shv[i] = src[i];
    __syncthreads();
    const ushort* sh = (const ushort*)shv;

    const int per = (nEdges + ES - 1) / ES;
    const int e0  = es * per;
    int e1 = e0 + per; if (e1 > nEdges) e1 = nEdges;

    float acc = 0.0f;
#pragma unroll 2
    for (int e = e0 + tid; e < e1; e += 256) {
        const int   l = li[e];
        const int   r = ri[e];
        const float w = ew[e];
        const uint4 A = *(const uint4*)(sh + slotOf(l));   // 8 rows, left col
        const uint4 B = *(const uint4*)(sh + slotOf(r));   // 8 rows, right col
        float s = 0.0f;
        float d;
        d = bf_lo(A.x) - bf_lo(B.x); s = fmaf(d, d, s);
        d = bf_hi(A.x) - bf_hi(B.x); s = fmaf(d, d, s);
        d = bf_lo(A.y) - bf_lo(B.y); s = fmaf(d, d, s);
        d = bf_hi(A.y) - bf_hi(B.y); s = fmaf(d, d, s);
        d = bf_lo(A.z) - bf_lo(B.z); s = fmaf(d, d, s);
        d = bf_hi(A.z) - bf_hi(B.z); s = fmaf(d, d, s);
        d = bf_lo(A.w) - bf_lo(B.w); s = fmaf(d, d, s);
        d = bf_hi(A.w) - bf_hi(B.w); s = fmaf(d, d, s);
        acc = fmaf(w, s, acc);
    }

#pragma unroll
    for (int off = 32; off > 0; off >>= 1)
        acc += __shfl_down(acc, off, 64);
    if ((tid & 63) == 0) red[tid >> 6] = acc;
    __syncthreads();
    if (tid == 0)
        partials[blockIdx.x] = red[0] + red[1] + red[2] + red[3];
}

// ---------------------------------------------------------------------------
// K3: sum partials, scale. Single block, fixed order -> deterministic.
// ---------------------------------------------------------------------------
__global__ __launch_bounds__(1024) void final_reduce_kernel(
        const float* __restrict__ partials, int n, float scale,
        float* __restrict__ out) {
    float s = 0.0f;
    for (int i = threadIdx.x; i < n; i += blockDim.x) s += partials[i];
#pragma unroll
    for (int off = 32; off > 0; off >>= 1)
        s += __shfl_down(s, off, 64);

    __shared__ float smem[16];
    const int wave = threadIdx.x >> 6;
    const int lane = threadIdx.x & 63;
    if (lane == 0) smem[wave] = s;
    __syncthreads();
    if (threadIdx.x == 0) {
        float t = 0.0f;
        for (int i = 0; i < (int)(blockDim.x >> 6); ++i) t += smem[i];
        out[0] = scale * t;
    }
}

// ---------------------------------------------------------------------------
extern "C" void kernel_launch(void* const* d_in, const int* in_sizes, int n_in,
                              void* d_out, int out_size, void* d_ws, size_t ws_size,
                              hipStream_t stream) {
    const float* logits = (const float*)d_in[0];
    const float* labels = (const float*)d_in[1];
    const float* ew     = (const float*)d_in[2];
    const int*   li     = (const int*)d_in[3];
    const int*   ri     = (const int*)d_in[4];
    float* out          = (float*)d_out;

    const int nEdges = in_sizes[2];

    // workspace: yPack images (128 * 36000 B), partials (4 KB)
    uint4* yPack    = (uint4*)d_ws;
    float* partials = (float*)((char*)d_ws + (size_t)NRG * IMG_U16 * sizeof(ushort));

    convert_pack_kernel<<<NRG * K1_SL, 256, 0, stream>>>(logits, labels, yPack);

    edge_reduce_kernel<<<NB2, 256, 0, stream>>>(yPack, ew, li, ri, nEdges, partials);

    const float scale = LAMBDA_SMOOTH / ((float)BATCH * (float)nEdges);
    final_reduce_kernel<<<1, 1024, 0, stream>>>(partials, NB2, scale, out);
}